// Round 14
// baseline (149.624 us; speedup 1.0000x reference)
//
#include <hip/hip_runtime.h>
#include <math.h>

#define DI 1024
#define DM 2048
#define DS 16
#define LSEQ 1024
#define NB 2
#define NTOK (NB * LSEQ)
#define TC 128         // scan output chunk
#define WU 32          // scan warm-up window (coeff <= ~0.55/step => err < 1e-7)
#define LDU 164        // ushort LDS row stride for S/V
#define NRP 161        // float4-row stride for B/C quads
#define ZLD 68         // Zsh row stride

typedef unsigned short ushort_t;
typedef __attribute__((ext_vector_type(8))) short short8;
typedef __attribute__((ext_vector_type(4))) float f32x4;

__device__ __forceinline__ float bf2f(ushort_t u) {
    union { unsigned u; float f; } c; c.u = (unsigned)u << 16; return c.f;
}
__device__ __forceinline__ ushort_t f2bf(float f) {
    union { float f; unsigned u; } c; c.f = f;
    unsigned r = c.u + 0x7FFFu + ((c.u >> 16) & 1u);
    return (ushort_t)(r >> 16);
}

// async global->LDS, 16B per lane. LDS dest is wave-uniform base + lane*16.
__device__ __forceinline__ void gload16(const void* g, void* l) {
    __builtin_amdgcn_global_load_lds(
        (const __attribute__((address_space(1))) void*)g,
        (__attribute__((address_space(3))) void*)l, 16, 0, 0);
}

// DPP 4-lane (quad) sum: xor1, xor2. Pure VALU, quad-aligned groups.
template<int CTRL>
__device__ __forceinline__ float dpp_mv(float v) {
    int r = __builtin_amdgcn_update_dpp(0, __builtin_bit_cast(int, v), CTRL, 0xF, 0xF, true);
    return __builtin_bit_cast(float, r);
}
__device__ __forceinline__ float sum4(float v) {
    v += dpp_mv<0xB1>(v);    // quad_perm [1,0,3,2] : xor 1
    v += dpp_mv<0x4E>(v);    // quad_perm [2,3,0,1] : xor 2
    return v;
}

__device__ __forceinline__ void cvt4(const float* __restrict__ in,
                                     ushort_t* __restrict__ out, int q) {
    float4 v = ((const float4*)in)[q];
    ushort4 o;
    o.x = f2bf(v.x); o.y = f2bf(v.y); o.z = f2bf(v.z); o.w = f2bf(v.w);
    ((ushort4*)out)[q] = o;
}

// ---------------- prep: all f32->bf16 conversions + weight packing, one kernel ----------------
__global__ __launch_bounds__(256) void prep(
    const float* __restrict__ seq, const float* __restrict__ W_in,
    const float* __restrict__ W_out, const float* __restrict__ W_sD2,
    const float* __restrict__ Wb, const float* __restrict__ Wc,
    const float* __restrict__ Wd1,
    ushort_t* __restrict__ seq_bf, ushort_t* __restrict__ W_in_bf,
    ushort_t* __restrict__ W_out_bf, ushort_t* __restrict__ W_sD2_bf,
    ushort_t* __restrict__ wbcd)
{
    int q = blockIdx.x * 256 + threadIdx.x;
    if (q < 524288)        cvt4(seq,   seq_bf,   q);
    else if (q < 1572864)  cvt4(W_in,  W_in_bf,  q - 524288);
    else if (q < 2097152)  cvt4(W_out, W_out_bf, q - 1572864);
    else if (q < 2162688)  cvt4(W_sD2, W_sD2_bf, q - 2097152);
    else {
        int p = q - 2162688;          // quad within wbcd [256][2048]
        int idx = p * 4;
        int row = idx >> 11, col = idx & (DM - 1);
        float4 v = make_float4(0.f, 0.f, 0.f, 0.f);
        if (row < 16)       v = *(const float4*)&Wb[row * DM + col];
        else if (row < 32)  v = *(const float4*)&Wc[(row - 16) * DM + col];
        else if (row < 160) v = *(const float4*)&Wd1[(row - 32) * DM + col];
        ushort4 o;
        o.x = f2bf(v.x); o.y = f2bf(v.y); o.z = f2bf(v.z); o.w = f2bf(v.w);
        ((ushort4*)wbcd)[p] = o;
    }
}

// ---------------- bf16 MFMA GEMM (2-phase dbuf prefetch + XCD swizzle) ----------------
// C[M,N] = epi( A[M,K] @ B[N,K]^T ). 4 waves (2x2), tile TM x 128, 16x16x32 mfma.
// AF32: A is a single f32 matrix (reg-staged, cvt to bf16, swizzled ds_write; single-buffered).
// EPI: 0=f32 out, 1=bf16 out, 3=bf16 softplus(bias[col]+x), 6=f32 atomicAdd into Cout
template<int TM, int EPI, bool AF32 = false>
__global__ __launch_bounds__(256) void gemm_bt(
    const ushort_t* __restrict__ A, const ushort_t* __restrict__ B,
    void* __restrict__ Cout, int K, int lda, int ldb, int ldc,
    const float* __restrict__ bias)
{
    constexpr int MF = TM / 32;            // M-frags per wave
    constexpr int ASZ = TM * 32;
    constexpr int BSZ = 128 * 32;
    __shared__ ushort_t As[2 * ASZ];
    __shared__ ushort_t Bs[2 * BSZ];
    const int tid = threadIdx.x;
    const int lane = tid & 63;
    const int wv = tid >> 6;
    const int wr = wv >> 1, wc = wv & 1;

    // XCD-aware bijective remap (m204) of the (x,y) plane
    const int gx = gridDim.x, gy = gridDim.y;
    const int nwg = gx * gy;
    const int orig = blockIdx.y * gx + blockIdx.x;
    const int q8 = nwg >> 3, r8 = nwg & 7;
    const int xcd = orig & 7, i8 = orig >> 3;
    const int wg = ((xcd < r8) ? xcd * (q8 + 1) : r8 * (q8 + 1) + (xcd - r8) * q8) + i8;
    const int bm = (wg / gx) * TM, bn = (wg % gx) * 128;

    int kbeg = 0, kend = K;
    if (gridDim.z > 1) { int ks = K / gridDim.z; kbeg = blockIdx.z * ks; kend = kbeg + ks; }

    f32x4 acc[MF][4];
#pragma unroll
    for (int m = 0; m < MF; ++m)
#pragma unroll
        for (int n = 0; n < 4; ++n) acc[m][n] = (f32x4){0.f, 0.f, 0.f, 0.f};

    const int r_lo = lane >> 2;
    const int s_l = lane & 3;
    const int row0 = wv * 16 + r_lo;
    const int row1 = 64 + wv * 16 + r_lo;
    const int sg0 = s_l ^ ((row0 >> 1) & 3);
    const int sg1 = s_l ^ ((row1 >> 1) & 3);
    const ushort_t* gB0 = B + (size_t)(bn + row0) * ldb + sg0 * 8;
    const ushort_t* gB1 = B + (size_t)(bn + row1) * ldb + sg1 * 8;
    const int lB0o = (wv * 16) * 32;
    const int lB1o = (64 + wv * 16) * 32;

    if constexpr (AF32) {
        // single-buffered: A reg-staged from f32 (cvt->bf16->swizzled ds_write), B via gload16.
        const int r = tid >> 2, s = tid & 3;
        const int sg = s ^ ((r >> 1) & 3);
        const float* pA = reinterpret_cast<const float*>(A) + (size_t)(bm + r) * lda + sg * 8;
        for (int k = kbeg; k < kend; k += 32) {
            gload16(gB0 + k, &Bs[lB0o]);
            gload16(gB1 + k, &Bs[lB1o]);
            float4 v0 = *(const float4*)(pA + k);
            float4 v1 = *(const float4*)(pA + k + 4);
            ushort4 o0, o1;
            o0.x = f2bf(v0.x); o0.y = f2bf(v0.y); o0.z = f2bf(v0.z); o0.w = f2bf(v0.w);
            o1.x = f2bf(v1.x); o1.y = f2bf(v1.y); o1.z = f2bf(v1.z); o1.w = f2bf(v1.w);
            *(ushort4*)&As[r * 32 + s * 8] = o0;
            *(ushort4*)&As[r * 32 + s * 8 + 4] = o1;
            __syncthreads();                // A written, B resident (vmcnt drained)
            short8 af[MF], bfr[4];
#pragma unroll
            for (int m = 0; m < MF; ++m) {
                int row = wr * (TM / 2) + m * 16 + (lane & 15);
                int sl = (lane >> 4) ^ ((row >> 1) & 3);
                af[m] = *(const short8*)&As[row * 32 + sl * 8];
            }
#pragma unroll
            for (int n = 0; n < 4; ++n) {
                int row = wc * 64 + n * 16 + (lane & 15);
                int sl = (lane >> 4) ^ ((row >> 1) & 3);
                bfr[n] = *(const short8*)&Bs[row * 32 + sl * 8];
            }
#pragma unroll
            for (int m = 0; m < MF; ++m)
#pragma unroll
                for (int n = 0; n < 4; ++n)
                    acc[m][n] = __builtin_amdgcn_mfma_f32_16x16x32_bf16(af[m], bfr[n], acc[m][n], 0, 0, 0);
            __syncthreads();                // LDS safe to overwrite
        }
    } else {
        const ushort_t* gA0 = A + (size_t)(bm + row0) * lda + sg0 * 8;
        const ushort_t* gA1 = A + (size_t)(bm + row1) * lda + sg1 * 8;   // TM=128 only
        const int lA0o = (wv * 16) * 32;
        const int lA1o = ((TM == 128 ? 64 : 0) + wv * 16) * 32;

        // prologue: stage first tile into buf 0
        gload16(gA0 + kbeg, &As[lA0o]);
        if (TM == 128) gload16(gA1 + kbeg, &As[lA1o]);
        gload16(gB0 + kbeg, &Bs[lB0o]);
        gload16(gB1 + kbeg, &Bs[lB1o]);
        __syncthreads();

        int cur = 0;
        for (int k = kbeg; k < kend; k += 32) {
            const int nxt = cur ^ 1;
            if (k + 32 < kend) {               // prefetch tile t+1 (overlaps compute of t)
                gload16(gA0 + k + 32, &As[nxt * ASZ + lA0o]);
                if (TM == 128) gload16(gA1 + k + 32, &As[nxt * ASZ + lA1o]);
                gload16(gB0 + k + 32, &Bs[nxt * BSZ + lB0o]);
                gload16(gB1 + k + 32, &Bs[nxt * BSZ + lB1o]);
            }
            const int ca = cur * ASZ, cb = cur * BSZ;
            short8 af[MF], bfr[4];
#pragma unroll
            for (int m = 0; m < MF; ++m) {
                int row = wr * (TM / 2) + m * 16 + (lane & 15);
                int sl = (lane >> 4) ^ ((row >> 1) & 3);
                af[m] = *(const short8*)&As[ca + row * 32 + sl * 8];
            }
#pragma unroll
            for (int n = 0; n < 4; ++n) {
                int row = wc * 64 + n * 16 + (lane & 15);
                int sl = (lane >> 4) ^ ((row >> 1) & 3);
                bfr[n] = *(const short8*)&Bs[cb + row * 32 + sl * 8];
            }
#pragma unroll
            for (int m = 0; m < MF; ++m)
#pragma unroll
                for (int n = 0; n < 4; ++n)
                    acc[m][n] = __builtin_amdgcn_mfma_f32_16x16x32_bf16(af[m], bfr[n], acc[m][n], 0, 0, 0);
            __syncthreads();                   // drains vmcnt: next tile resident, cur reads done
            cur = nxt;
        }
    }

    const int orow = bm + wr * (TM / 2) + ((lane >> 4) << 2);
    const int ocol = bn + wc * 64 + (lane & 15);
#pragma unroll
    for (int m = 0; m < MF; ++m)
#pragma unroll
        for (int n = 0; n < 4; ++n) {
            int col = ocol + n * 16;
#pragma unroll
            for (int r = 0; r < 4; ++r) {
                int row = orow + m * 16 + r;
                float v = acc[m][n][r];
                if (EPI == 3) {
                    v += bias[col];
                    v = (v > 20.f) ? v : __logf(1.f + __expf(v));
                    ((ushort_t*)Cout)[(size_t)row * ldc + col] = f2bf(v);
                } else if (EPI == 1) {
                    ((ushort_t*)Cout)[(size_t)row * ldc + col] = f2bf(v);
                } else if (EPI == 6) {
                    atomicAdd(&((float*)Cout)[(size_t)row * ldc + col], v);
                } else {
                    ((float*)Cout)[(size_t)row * ldc + col] = v;
                }
            }
        }
}

// ---------------- causal depthwise conv (K=4) + bias + SiLU; 8 d's/thread, ushort8 I/O ----------------
// also zeroes bcd1f [2048 x 256] f32 (one row per block) ahead of smallK's atomic accumulation.
__global__ __launch_bounds__(256) void conv_silu(const ushort_t* __restrict__ ab,
                                                 const float* __restrict__ w,
                                                 const float* __restrict__ bias,
                                                 ushort_t* __restrict__ outh,
                                                 float* __restrict__ bcd1f) {
    const int bt = blockIdx.x;              // one token per block
    const int b = bt >> 10, t = bt & (LSEQ - 1);
    const int d = threadIdx.x * 8;

    bcd1f[(size_t)bt * 256 + threadIdx.x] = 0.f;

    float wv[8][4];
#pragma unroll
    for (int j = 0; j < 8; ++j) {
        float4 tw = *(const float4*)&w[(d + j) * 4];
        wv[j][0] = tw.x; wv[j][1] = tw.y; wv[j][2] = tw.z; wv[j][3] = tw.w;
    }
    float accv[8];
    {
        float4 b0 = *(const float4*)&bias[d];
        float4 b1 = *(const float4*)&bias[d + 4];
        accv[0] = b0.x; accv[1] = b0.y; accv[2] = b0.z; accv[3] = b0.w;
        accv[4] = b1.x; accv[5] = b1.y; accv[6] = b1.z; accv[7] = b1.w;
    }
#pragma unroll
    for (int k = 0; k < 4; ++k) {
        int tt = t + k - 3;
        if (tt >= 0) {
            short8 av = *(const short8*)&ab[(size_t)(b * LSEQ + tt) * (2 * DM) + d];
#pragma unroll
            for (int j = 0; j < 8; ++j)
                accv[j] = fmaf(bf2f((ushort_t)av[j]), wv[j][k], accv[j]);
        }
    }
    short8 o;
#pragma unroll
    for (int j = 0; j < 8; ++j) {
        float s = accv[j] / (1.f + __expf(-accv[j]));
        o[j] = (short)f2bf(s);
    }
    *(short8*)&outh[(size_t)bt * DM + d] = o;
}

// ---------------- windowed scan v3: 4 states/thread, 64 d's/block ----------------
// q = tid&3 owns states {4q..4q+3}; dl = tid>>2 owns d0+dl. B/C staged as direct f32
// float4 copies from bcd1f. Also zeroes `out` ahead of G8's atomic accumulation.
__global__ __launch_bounds__(256) void scan_win(
    const ushort_t* __restrict__ sdel, const ushort_t* __restrict__ aconv,
    const float* __restrict__ bcd1f, const ushort_t* __restrict__ ab,
    const float* __restrict__ A_param, const float* __restrict__ D_param,
    ushort_t* __restrict__ z, float* __restrict__ outZero)
{
    __shared__ ushort_t Ssh[64 * LDU];
    __shared__ ushort_t Vsh[64 * LDU];
    __shared__ float    Bq[4 * NRP * 4];   // [g][row] float4 = states {4g..4g+3}
    __shared__ float    Cq[4 * NRP * 4];
    __shared__ ushort_t Zsh[TC * ZLD];

    const int tid = threadIdx.x;
    const int d0 = blockIdx.x * 64;
    const int c = blockIdx.y, b = blockIdx.z;
    const int nw = (c == 0) ? 0 : WU;
    const int nrows = nw + TC;
    const int tok0 = b * LSEQ + c * TC - nw;      // first staged token
    const int tokout0 = b * LSEQ + c * TC;        // first output token

    // zero `out` (2M floats over 512 blocks = 4 float4/thread), ahead of G8 atomics
    {
        const int bid = blockIdx.x + (blockIdx.y << 5) + (blockIdx.z << 8);
        float4 z4 = make_float4(0.f, 0.f, 0.f, 0.f);
#pragma unroll
        for (int j = 0; j < 4; ++j)
            ((float4*)outZero)[(size_t)bid * 1024 + j * 256 + tid] = z4;
    }

    // S/V staging: 4-row blocks, transposed ushort4 writes (b64)
    for (int j = tid; j < (nrows / 4) * 32; j += 256) {
        int a = j & 1;
        int r = j >> 1;
        int cq = (r & 15) * 4;
        int row4 = (r >> 4) * 4;
        const ushort_t* src = (a ? aconv : sdel) + (size_t)(tok0 + row4) * DM + d0 + cq;
        ushort4 v0 = *(const ushort4*)(src);
        ushort4 v1 = *(const ushort4*)(src + DM);
        ushort4 v2 = *(const ushort4*)(src + 2 * DM);
        ushort4 v3 = *(const ushort4*)(src + 3 * DM);
        ushort_t* dst = (a ? Vsh : Ssh) + row4;
        *(ushort4*)(dst + (cq + 0) * LDU) = make_ushort4(v0.x, v1.x, v2.x, v3.x);
        *(ushort4*)(dst + (cq + 1) * LDU) = make_ushort4(v0.y, v1.y, v2.y, v3.y);
        *(ushort4*)(dst + (cq + 2) * LDU) = make_ushort4(v0.z, v1.z, v2.z, v3.z);
        *(ushort4*)(dst + (cq + 3) * LDU) = make_ushort4(v0.w, v1.w, v2.w, v3.w);
    }
    // B staging (all staged rows): direct f32 float4 copy
    for (int j = tid; j < nrows * 4; j += 256) {
        int row = j >> 2, g = j & 3;
        float4 f = *(const float4*)&bcd1f[(size_t)(tok0 + row) * 256 + 4 * g];
        *(float4*)&Bq[(g * NRP + row) * 4] = f;
    }
    // C staging (output rows only)
    for (int j = tid; j < TC * 4; j += 256) {
        int row = nw + (j >> 2), g = j & 3;
        float4 f = *(const float4*)&bcd1f[(size_t)(tok0 + row) * 256 + 16 + 4 * g];
        *(float4*)&Cq[(g * NRP + row) * 4] = f;
    }
    __syncthreads();

    const int q = tid & 3, dl = tid >> 2;
    const int d = d0 + dl;
    float4 av4 = *(const float4*)&A_param[d * DS + 4 * q];
    const float ea0 = __expf(-av4.x), ea1 = __expf(-av4.y);
    const float ea2 = __expf(-av4.z), ea3 = __expf(-av4.w);
    const float Dp = D_param[d];
    float h0 = 0.f, h1 = 0.f, h2 = 0.f, h3 = 0.f;

#define SCAN_STEP_WU(SD, AV, BI) {                                    \
        float sd = (SD), x = sd * (AV);                               \
        float4 Bv = *(const float4*)&Bq[(q * NRP + (BI)) * 4];        \
        h0 = fmaf(sd * ea0, h0, x * Bv.x);                           \
        h1 = fmaf(sd * ea1, h1, x * Bv.y);                           \
        h2 = fmaf(sd * ea2, h2, x * Bv.z);                           \
        h3 = fmaf(sd * ea3, h3, x * Bv.w); }

    // warm-up (no output)
    for (int i4 = 0; i4 < nw; i4 += 4) {
        ushort4 sdv = *(const ushort4*)&Ssh[dl * LDU + i4];
        ushort4 avv = *(const ushort4*)&Vsh[dl * LDU + i4];
        SCAN_STEP_WU(bf2f(sdv.x), bf2f(avv.x), i4 + 0);
        SCAN_STEP_WU(bf2f(sdv.y), bf2f(avv.y), i4 + 1);
        SCAN_STEP_WU(bf2f(sdv.z), bf2f(avv.z), i4 + 2);
        SCAN_STEP_WU(bf2f(sdv.w), bf2f(avv.w), i4 + 3);
    }

#define SCAN_STEP_OUT(SD, AV, BI, RV) {                               \
        float sd = (SD), av_ = (AV), x = sd * av_;                    \
        float4 Bv = *(const float4*)&Bq[(q * NRP + (BI)) * 4];        \
        float4 Cv = *(const float4*)&Cq[(q * NRP + (BI)) * 4];        \
        h0 = fmaf(sd * ea0, h0, x * Bv.x);                           \
        h1 = fmaf(sd * ea1, h1, x * Bv.y);                           \
        h2 = fmaf(sd * ea2, h2, x * Bv.z);                           \
        h3 = fmaf(sd * ea3, h3, x * Bv.w);                           \
        float r = h0 * Cv.x;                                          \
        r = fmaf(h1, Cv.y, r); r = fmaf(h2, Cv.z, r);                 \
        r = fmaf(h3, Cv.w, r);                                        \
        r = sum4(r);                                                  \
        RV = fmaf(Dp, av_, r); }

    // output region
    for (int i4 = nw; i4 < nrows; i4 += 4) {
        ushort4 sdv = *(const ushort4*)&Ssh[dl * LDU + i4];
        ushort4 avv = *(const ushort4*)&Vsh[dl * LDU + i4];
        float rv0, rv1, rv2, rv3;
        SCAN_STEP_OUT(bf2f(sdv.x), bf2f(avv.x), i4 + 0, rv0);
        SCAN_STEP_OUT(bf2f(sdv.y), bf2f(avv.y), i4 + 1, rv1);
        SCAN_STEP_OUT(bf2f(sdv.z), bf2f(avv.z), i4 + 2, rv2);
        SCAN_STEP_OUT(bf2f(sdv.w), bf2f(avv.w), i4 + 3, rv3);
        // lane q stores output step io+q (static select)
        float rvq = (q == 0) ? rv0 : (q == 1) ? rv1 : (q == 2) ? rv2 : rv3;
        int io = i4 - nw;
        Zsh[(io + q) * ZLD + dl] = f2bf(rvq);
    }
    __syncthreads();
    // write z with fused silu(g) gate (g read coalesced from global)
    for (int j = tid; j < TC * 16; j += 256) {
        int row = j >> 4, cq = (j & 15) * 4;
        ushort4 ov = *(const ushort4*)&Zsh[row * ZLD + cq];
        ushort4 gv = *(const ushort4*)&ab[(size_t)(tokout0 + row) * (2 * DM) + DM + d0 + cq];
        ushort4 o;
        float g0 = bf2f(gv.x), g1 = bf2f(gv.y), g2 = bf2f(gv.z), g3 = bf2f(gv.w);
        o.x = f2bf(bf2f(ov.x) * (g0 / (1.f + __expf(-g0))));
        o.y = f2bf(bf2f(ov.y) * (g1 / (1.f + __expf(-g1))));
        o.z = f2bf(bf2f(ov.z) * (g2 / (1.f + __expf(-g2))));
        o.w = f2bf(bf2f(ov.w) * (g3 / (1.f + __expf(-g3))));
        *(ushort4*)&z[(size_t)(tokout0 + row) * DM + d0 + cq] = o;
    }
#undef SCAN_STEP_WU
#undef SCAN_STEP_OUT
}

extern "C" void kernel_launch(void* const* d_in, const int* in_sizes, int n_in,
                              void* d_out, int out_size, void* d_ws, size_t ws_size,
                              hipStream_t stream) {
    const float* seq    = (const float*)d_in[0];
    const float* W_in   = (const float*)d_in[1];
    const float* W_out  = (const float*)d_in[2];
    const float* W_sB   = (const float*)d_in[3];
    const float* W_sC   = (const float*)d_in[4];
    const float* W_sD1  = (const float*)d_in[5];
    const float* W_sD2  = (const float*)d_in[6];
    const float* conv_w = (const float*)d_in[7];
    const float* conv_b = (const float*)d_in[8];
    const float* A_par  = (const float*)d_in[9];
    const float* D_par  = (const float*)d_in[10];
    float* out = (float*)d_out;

    char* ws = (char*)d_ws;
    const size_t MiB = 1024 * 1024;
    ushort_t* ab_bf    = (ushort_t*)(ws);                        // 16 MiB @0   (G1 -> conv, scan)
    ushort_t* aconv_h  = (ushort_t*)(ws + 16 * MiB);             //  8 MiB @16
    ushort_t* sdel_h   = (ushort_t*)(ws + 24 * MiB);             //  8 MiB @24
    ushort_t* W_out_bf = (ushort_t*)(ws + 32 * MiB);             //  4 MiB @32
    ushort_t* W_sD2_bf = (ushort_t*)(ws + 37 * MiB);             // .5 MiB @37
    ushort_t* Wbcd     = (ushort_t*)(ws + 37 * MiB + 512*1024);  //  1 MiB
    ushort_t* seq_bf   = (ushort_t*)(ws + 39 * MiB);             //  4 MiB @39  (dead after G1)
    ushort_t* W_in_bf  = (ushort_t*)(ws + 43 * MiB);             //  8 MiB @43  (dead after G1)
    float*    bcd1f    = (float*)(ws + 43 * MiB);                //  2 MiB @43  (over dead W_in_bf; conv zeroes, smallK atomics)
    ushort_t* z_bf     = (ushort_t*)(ws + 63 * MiB);             //  8 MiB @63  (scan -> G8)

    dim3 blk(256);

    // 1) all conversions + weight packing
    prep<<<dim3(8960), blk, 0, stream>>>(seq, W_in, W_out, W_sD2, W_sB, W_sC, W_sD1,
                                         seq_bf, W_in_bf, W_out_bf, W_sD2_bf, Wbcd);

    // 2) G1: ab = seq @ W_in^T (bf16 out)  M=2048 N=4096 K=1024, TM=64 -> 1024 blocks
    gemm_bt<64, 1><<<dim3(32, 32), blk, 0, stream>>>(seq_bf, W_in_bf, ab_bf, 1024, DI, DI, 2 * DM, nullptr);

    // 3) aconv = silu(causal_conv(a) + b) (bf16) + zero bcd1f
    conv_silu<<<dim3(NTOK), blk, 0, stream>>>(ab_bf, conv_w, conv_b, aconv_h, bcd1f);

    // 4) smallK split-K=8: bcd1f += aconv @ Wbcd^T slice (f32 atomic)  N=256, K=256/slice
    gemm_bt<64, 6><<<dim3(2, 32, 8), blk, 0, stream>>>(aconv_h, Wbcd, bcd1f, DM, DM, DM, 256, nullptr);

    // 5) G6: sdel = softplus(D + d1 @ W_sD2^T) (bf16 out)  N=2048 K=128
    //    A = bcd1f cols 32..159 (f32, AF32 reg-staged path)
    gemm_bt<64, 3, true><<<dim3(16, 32), blk, 0, stream>>>(
        (const ushort_t*)(bcd1f + 32), W_sD2_bf, sdel_h, 128, 256, 128, DM, D_par);

    // 6) windowed scan v3 -> z (B/C direct f32 from bcd1f) + zero out for G8 atomics
    scan_win<<<dim3(DM / 64, LSEQ / TC, NB), blk, 0, stream>>>(
        sdel_h, aconv_h, bcd1f, ab_bf, A_par, D_par, z_bf, out);

    // 7) G8 split-K=4: out += z @ W_out^T slice (f32 atomic)  N=1024, K=512/slice -> 1024 blocks
    gemm_bt<64, 6><<<dim3(8, 32, 4), blk, 0, stream>>>(z_bf, W_out_bf, out, DM, DM, DM, DI, nullptr);
}

// Round 15
// 129.664 us; speedup vs baseline: 1.1539x; 1.1539x over previous
//
#include <hip/hip_runtime.h>
#include <math.h>

#define DI 1024
#define DM 2048
#define DS 16
#define LSEQ 1024
#define NB 2
#define NTOK (NB * LSEQ)
#define TC 128         // scan output chunk
#define WU 32          // scan warm-up window (coeff <= ~0.55/step => err < 1e-7)
#define LDU 164        // ushort LDS row stride for S/V
#define NRP 161        // float4-row stride for B/C quads
#define ZLD 68         // Zsh row stride
#define NZ 8           // smallK split-K partial count

typedef unsigned short ushort_t;
typedef __attribute__((ext_vector_type(8))) short short8;
typedef __attribute__((ext_vector_type(4))) float f32x4;

__device__ __forceinline__ float bf2f(ushort_t u) {
    union { unsigned u; float f; } c; c.u = (unsigned)u << 16; return c.f;
}
__device__ __forceinline__ ushort_t f2bf(float f) {
    union { float f; unsigned u; } c; c.f = f;
    unsigned r = c.u + 0x7FFFu + ((c.u >> 16) & 1u);
    return (ushort_t)(r >> 16);
}

// async global->LDS, 16B per lane. LDS dest is wave-uniform base + lane*16.
__device__ __forceinline__ void gload16(const void* g, void* l) {
    __builtin_amdgcn_global_load_lds(
        (const __attribute__((address_space(1))) void*)g,
        (__attribute__((address_space(3))) void*)l, 16, 0, 0);
}

// DPP 4-lane (quad) sum: xor1, xor2. Pure VALU, quad-aligned groups.
template<int CTRL>
__device__ __forceinline__ float dpp_mv(float v) {
    int r = __builtin_amdgcn_update_dpp(0, __builtin_bit_cast(int, v), CTRL, 0xF, 0xF, true);
    return __builtin_bit_cast(float, r);
}
__device__ __forceinline__ float sum4(float v) {
    v += dpp_mv<0xB1>(v);    // quad_perm [1,0,3,2] : xor 1
    v += dpp_mv<0x4E>(v);    // quad_perm [2,3,0,1] : xor 2
    return v;
}

__device__ __forceinline__ void cvt4(const float* __restrict__ in,
                                     ushort_t* __restrict__ out, int q) {
    float4 v = ((const float4*)in)[q];
    ushort4 o;
    o.x = f2bf(v.x); o.y = f2bf(v.y); o.z = f2bf(v.z); o.w = f2bf(v.w);
    ((ushort4*)out)[q] = o;
}

// ---------------- prep: all f32->bf16 conversions + weight packing, one kernel ----------------
__global__ __launch_bounds__(256) void prep(
    const float* __restrict__ seq, const float* __restrict__ W_in,
    const float* __restrict__ W_out, const float* __restrict__ W_sD2,
    const float* __restrict__ Wb, const float* __restrict__ Wc,
    const float* __restrict__ Wd1,
    ushort_t* __restrict__ seq_bf, ushort_t* __restrict__ W_in_bf,
    ushort_t* __restrict__ W_out_bf, ushort_t* __restrict__ W_sD2_bf,
    ushort_t* __restrict__ wbcd)
{
    int q = blockIdx.x * 256 + threadIdx.x;
    if (q < 524288)        cvt4(seq,   seq_bf,   q);
    else if (q < 1572864)  cvt4(W_in,  W_in_bf,  q - 524288);
    else if (q < 2097152)  cvt4(W_out, W_out_bf, q - 1572864);
    else if (q < 2162688)  cvt4(W_sD2, W_sD2_bf, q - 2097152);
    else {
        int p = q - 2162688;          // quad within wbcd [256][2048]
        int idx = p * 4;
        int row = idx >> 11, col = idx & (DM - 1);
        float4 v = make_float4(0.f, 0.f, 0.f, 0.f);
        if (row < 16)       v = *(const float4*)&Wb[row * DM + col];
        else if (row < 32)  v = *(const float4*)&Wc[(row - 16) * DM + col];
        else if (row < 160) v = *(const float4*)&Wd1[(row - 32) * DM + col];
        ushort4 o;
        o.x = f2bf(v.x); o.y = f2bf(v.y); o.z = f2bf(v.z); o.w = f2bf(v.w);
        ((ushort4*)wbcd)[p] = o;
    }
}

// ---------------- bf16 MFMA GEMM (2-phase dbuf prefetch + XCD swizzle) ----------------
// C[M,N] = epi( A[M,K] @ B[N,K]^T ). 4 waves (2x2), tile TM x 128, 16x16x32 mfma.
// ASUM8: A is the sum of NZ bf16 split-K partials; reg-staged + swizzled ds_write.
// EPI: 0=f32 out, 1=bf16 out, 3=bf16 softplus(bias[col]+x), 5=bf16 split-K partial
template<int TM, int EPI, bool ASUM8 = false>
__global__ __launch_bounds__(256) void gemm_bt(
    const ushort_t* __restrict__ A, const ushort_t* __restrict__ B,
    void* __restrict__ Cout, int K, int lda, int ldb, int ldc,
    const float* __restrict__ bias, void* __restrict__ Cpart, size_t pstride)
{
    constexpr int MF = TM / 32;            // M-frags per wave
    constexpr int ASZ = TM * 32;
    constexpr int BSZ = 128 * 32;
    __shared__ ushort_t As[2 * ASZ];
    __shared__ ushort_t Bs[2 * BSZ];
    const int tid = threadIdx.x;
    const int lane = tid & 63;
    const int wv = tid >> 6;
    const int wr = wv >> 1, wc = wv & 1;

    // XCD-aware bijective remap (m204) of the (x,y) plane
    const int gx = gridDim.x, gy = gridDim.y;
    const int nwg = gx * gy;
    const int orig = blockIdx.y * gx + blockIdx.x;
    const int q8 = nwg >> 3, r8 = nwg & 7;
    const int xcd = orig & 7, i8 = orig >> 3;
    const int wg = ((xcd < r8) ? xcd * (q8 + 1) : r8 * (q8 + 1) + (xcd - r8) * q8) + i8;
    const int bm = (wg / gx) * TM, bn = (wg % gx) * 128;

    int kbeg = 0, kend = K;
    if (EPI == 5) { int ks = K / gridDim.z; kbeg = blockIdx.z * ks; kend = kbeg + ks; }

    f32x4 acc[MF][4];
#pragma unroll
    for (int m = 0; m < MF; ++m)
#pragma unroll
        for (int n = 0; n < 4; ++n) acc[m][n] = (f32x4){0.f, 0.f, 0.f, 0.f};

    const int r_lo = lane >> 2;
    const int s_l = lane & 3;
    const int row0 = wv * 16 + r_lo;
    const int row1 = 64 + wv * 16 + r_lo;
    const int sg0 = s_l ^ ((row0 >> 1) & 3);
    const int sg1 = s_l ^ ((row1 >> 1) & 3);
    const ushort_t* gB0 = B + (size_t)(bn + row0) * ldb + sg0 * 8;
    const ushort_t* gB1 = B + (size_t)(bn + row1) * ldb + sg1 * 8;
    const int lB0o = (wv * 16) * 32;
    const int lB1o = (64 + wv * 16) * 32;

    if constexpr (ASUM8) {
        // single-buffered: A reg-staged with 8-partial sum, B via gload16.
        const int r = tid >> 2, s = tid & 3;
        const int sg = s ^ ((r >> 1) & 3);
        const ushort_t* gA = A + (size_t)(bm + r) * lda + sg * 8;
        for (int k = kbeg; k < kend; k += 32) {
            gload16(gB0 + k, &Bs[lB0o]);
            gload16(gB1 + k, &Bs[lB1o]);
            float fa[8];
#pragma unroll
            for (int j = 0; j < 8; ++j) fa[j] = 0.f;
#pragma unroll
            for (int zz = 0; zz < NZ; ++zz) {
                const ushort_t* p = gA + (size_t)zz * pstride + k;
                ushort4 v0 = *(const ushort4*)p;
                ushort4 v1 = *(const ushort4*)(p + 4);
                fa[0] += bf2f(v0.x); fa[1] += bf2f(v0.y);
                fa[2] += bf2f(v0.z); fa[3] += bf2f(v0.w);
                fa[4] += bf2f(v1.x); fa[5] += bf2f(v1.y);
                fa[6] += bf2f(v1.z); fa[7] += bf2f(v1.w);
            }
            ushort4 o0, o1;
            o0.x = f2bf(fa[0]); o0.y = f2bf(fa[1]); o0.z = f2bf(fa[2]); o0.w = f2bf(fa[3]);
            o1.x = f2bf(fa[4]); o1.y = f2bf(fa[5]); o1.z = f2bf(fa[6]); o1.w = f2bf(fa[7]);
            *(ushort4*)&As[r * 32 + s * 8] = o0;
            *(ushort4*)&As[r * 32 + s * 8 + 4] = o1;
            __syncthreads();                // A written, B resident (vmcnt drained)
            short8 af[MF], bfr[4];
#pragma unroll
            for (int m = 0; m < MF; ++m) {
                int row = wr * (TM / 2) + m * 16 + (lane & 15);
                int sl = (lane >> 4) ^ ((row >> 1) & 3);
                af[m] = *(const short8*)&As[row * 32 + sl * 8];
            }
#pragma unroll
            for (int n = 0; n < 4; ++n) {
                int row = wc * 64 + n * 16 + (lane & 15);
                int sl = (lane >> 4) ^ ((row >> 1) & 3);
                bfr[n] = *(const short8*)&Bs[row * 32 + sl * 8];
            }
#pragma unroll
            for (int m = 0; m < MF; ++m)
#pragma unroll
                for (int n = 0; n < 4; ++n)
                    acc[m][n] = __builtin_amdgcn_mfma_f32_16x16x32_bf16(af[m], bfr[n], acc[m][n], 0, 0, 0);
            __syncthreads();                // LDS safe to overwrite
        }
    } else {
        const ushort_t* gA0 = A + (size_t)(bm + row0) * lda + sg0 * 8;
        const ushort_t* gA1 = A + (size_t)(bm + row1) * lda + sg1 * 8;   // TM=128 only
        const int lA0o = (wv * 16) * 32;
        const int lA1o = ((TM == 128 ? 64 : 0) + wv * 16) * 32;

        // prologue: stage first tile into buf 0
        gload16(gA0 + kbeg, &As[lA0o]);
        if (TM == 128) gload16(gA1 + kbeg, &As[lA1o]);
        gload16(gB0 + kbeg, &Bs[lB0o]);
        gload16(gB1 + kbeg, &Bs[lB1o]);
        __syncthreads();

        int cur = 0;
        for (int k = kbeg; k < kend; k += 32) {
            const int nxt = cur ^ 1;
            if (k + 32 < kend) {               // prefetch tile t+1 (overlaps compute of t)
                gload16(gA0 + k + 32, &As[nxt * ASZ + lA0o]);
                if (TM == 128) gload16(gA1 + k + 32, &As[nxt * ASZ + lA1o]);
                gload16(gB0 + k + 32, &Bs[nxt * BSZ + lB0o]);
                gload16(gB1 + k + 32, &Bs[nxt * BSZ + lB1o]);
            }
            const int ca = cur * ASZ, cb = cur * BSZ;
            short8 af[MF], bfr[4];
#pragma unroll
            for (int m = 0; m < MF; ++m) {
                int row = wr * (TM / 2) + m * 16 + (lane & 15);
                int sl = (lane >> 4) ^ ((row >> 1) & 3);
                af[m] = *(const short8*)&As[ca + row * 32 + sl * 8];
            }
#pragma unroll
            for (int n = 0; n < 4; ++n) {
                int row = wc * 64 + n * 16 + (lane & 15);
                int sl = (lane >> 4) ^ ((row >> 1) & 3);
                bfr[n] = *(const short8*)&Bs[cb + row * 32 + sl * 8];
            }
#pragma unroll
            for (int m = 0; m < MF; ++m)
#pragma unroll
                for (int n = 0; n < 4; ++n)
                    acc[m][n] = __builtin_amdgcn_mfma_f32_16x16x32_bf16(af[m], bfr[n], acc[m][n], 0, 0, 0);
            __syncthreads();                   // drains vmcnt: next tile resident, cur reads done
            cur = nxt;
        }
    }

    const int orow = bm + wr * (TM / 2) + ((lane >> 4) << 2);
    const int ocol = bn + wc * 64 + (lane & 15);
#pragma unroll
    for (int m = 0; m < MF; ++m)
#pragma unroll
        for (int n = 0; n < 4; ++n) {
            int col = ocol + n * 16;
#pragma unroll
            for (int r = 0; r < 4; ++r) {
                int row = orow + m * 16 + r;
                float v = acc[m][n][r];
                if (EPI == 3) {
                    v += bias[col];
                    v = (v > 20.f) ? v : __logf(1.f + __expf(v));
                    ((ushort_t*)Cout)[(size_t)row * ldc + col] = f2bf(v);
                } else if (EPI == 1) {
                    ((ushort_t*)Cout)[(size_t)row * ldc + col] = f2bf(v);
                } else if (EPI == 5) {
                    ((ushort_t*)Cpart + (size_t)blockIdx.z * pstride)[(size_t)row * ldc + col] = f2bf(v);
                } else {
                    ((float*)Cout)[(size_t)row * ldc + col] = v;
                }
            }
        }
}

// ---------------- split-K reduce (4 bf16 partials) -> f32 out ----------------
__global__ __launch_bounds__(256) void reduce_out(const ushort_t* __restrict__ part,
                                                  float* __restrict__ out)
{
    int q = blockIdx.x * 256 + threadIdx.x;   // over 524288 quads
    float sx = 0.f, sy = 0.f, sz = 0.f, sw = 0.f;
#pragma unroll
    for (int z = 0; z < 4; ++z) {
        ushort4 v = ((const ushort4*)part)[q + z * 524288];
        sx += bf2f(v.x); sy += bf2f(v.y); sz += bf2f(v.z); sw += bf2f(v.w);
    }
    float4 o; o.x = sx; o.y = sy; o.z = sz; o.w = sw;
    ((float4*)out)[q] = o;
}

// ---------------- causal depthwise conv (K=4) + bias + SiLU; 8 d's/thread, ushort8 I/O ----------------
__global__ __launch_bounds__(256) void conv_silu(const ushort_t* __restrict__ ab,
                                                 const float* __restrict__ w,
                                                 const float* __restrict__ bias,
                                                 ushort_t* __restrict__ outh) {
    const int bt = blockIdx.x;              // one token per block
    const int b = bt >> 10, t = bt & (LSEQ - 1);
    const int d = threadIdx.x * 8;

    float wv[8][4];
#pragma unroll
    for (int j = 0; j < 8; ++j) {
        float4 tw = *(const float4*)&w[(d + j) * 4];
        wv[j][0] = tw.x; wv[j][1] = tw.y; wv[j][2] = tw.z; wv[j][3] = tw.w;
    }
    float accv[8];
    {
        float4 b0 = *(const float4*)&bias[d];
        float4 b1 = *(const float4*)&bias[d + 4];
        accv[0] = b0.x; accv[1] = b0.y; accv[2] = b0.z; accv[3] = b0.w;
        accv[4] = b1.x; accv[5] = b1.y; accv[6] = b1.z; accv[7] = b1.w;
    }
#pragma unroll
    for (int k = 0; k < 4; ++k) {
        int tt = t + k - 3;
        if (tt >= 0) {
            short8 av = *(const short8*)&ab[(size_t)(b * LSEQ + tt) * (2 * DM) + d];
#pragma unroll
            for (int j = 0; j < 8; ++j)
                accv[j] = fmaf(bf2f((ushort_t)av[j]), wv[j][k], accv[j]);
        }
    }
    short8 o;
#pragma unroll
    for (int j = 0; j < 8; ++j) {
        float s = accv[j] / (1.f + __expf(-accv[j]));
        o[j] = (short)f2bf(s);
    }
    *(short8*)&outh[(size_t)bt * DM + d] = o;
}

// ---------------- windowed scan v3: 4 states/thread, 64 d's/block ----------------
// q = tid&3 owns states {4q..4q+3}; dl = tid>>2 owns d0+dl. B summed over NZ partials
// for all staged rows; C only for output rows (warm-up never reads C).
__global__ __launch_bounds__(256) void scan_win(
    const ushort_t* __restrict__ sdel, const ushort_t* __restrict__ aconv,
    const ushort_t* __restrict__ partK, const ushort_t* __restrict__ ab,
    const float* __restrict__ A_param, const float* __restrict__ D_param,
    ushort_t* __restrict__ z)
{
    __shared__ ushort_t Ssh[64 * LDU];
    __shared__ ushort_t Vsh[64 * LDU];
    __shared__ float    Bq[4 * NRP * 4];   // [g][row] float4 = states {4g..4g+3}
    __shared__ float    Cq[4 * NRP * 4];
    __shared__ ushort_t Zsh[TC * ZLD];

    const int tid = threadIdx.x;
    const int d0 = blockIdx.x * 64;
    const int c = blockIdx.y, b = blockIdx.z;
    const int nw = (c == 0) ? 0 : WU;
    const int nrows = nw + TC;
    const int tok0 = b * LSEQ + c * TC - nw;      // first staged token
    const int tokout0 = b * LSEQ + c * TC;        // first output token

    // S/V staging: 4-row blocks, transposed ushort4 writes (b64)
    for (int j = tid; j < (nrows / 4) * 32; j += 256) {
        int a = j & 1;
        int r = j >> 1;
        int cq = (r & 15) * 4;
        int row4 = (r >> 4) * 4;
        const ushort_t* src = (a ? aconv : sdel) + (size_t)(tok0 + row4) * DM + d0 + cq;
        ushort4 v0 = *(const ushort4*)(src);
        ushort4 v1 = *(const ushort4*)(src + DM);
        ushort4 v2 = *(const ushort4*)(src + 2 * DM);
        ushort4 v3 = *(const ushort4*)(src + 3 * DM);
        ushort_t* dst = (a ? Vsh : Ssh) + row4;
        *(ushort4*)(dst + (cq + 0) * LDU) = make_ushort4(v0.x, v1.x, v2.x, v3.x);
        *(ushort4*)(dst + (cq + 1) * LDU) = make_ushort4(v0.y, v1.y, v2.y, v3.y);
        *(ushort4*)(dst + (cq + 2) * LDU) = make_ushort4(v0.z, v1.z, v2.z, v3.z);
        *(ushort4*)(dst + (cq + 3) * LDU) = make_ushort4(v0.w, v1.w, v2.w, v3.w);
    }
    // B staging (all staged rows): sum NZ bf16 partials in f32
    for (int j = tid; j < nrows * 4; j += 256) {
        int row = j >> 2, g = j & 3;
        size_t off = (size_t)(tok0 + row) * 256 + 4 * g;
        float fx = 0.f, fy = 0.f, fz = 0.f, fw = 0.f;
#pragma unroll
        for (int zz = 0; zz < NZ; ++zz) {
            ushort4 v = *(const ushort4*)&partK[(size_t)zz * (2048 * 256) + off];
            fx += bf2f(v.x); fy += bf2f(v.y); fz += bf2f(v.z); fw += bf2f(v.w);
        }
        *(float4*)&Bq[(g * NRP + row) * 4] = make_float4(fx, fy, fz, fw);
    }
    // C staging (output rows only)
    for (int j = tid; j < TC * 4; j += 256) {
        int row = nw + (j >> 2), g = j & 3;
        size_t off = (size_t)(tok0 + row) * 256 + 16 + 4 * g;
        float fx = 0.f, fy = 0.f, fz = 0.f, fw = 0.f;
#pragma unroll
        for (int zz = 0; zz < NZ; ++zz) {
            ushort4 v = *(const ushort4*)&partK[(size_t)zz * (2048 * 256) + off];
            fx += bf2f(v.x); fy += bf2f(v.y); fz += bf2f(v.z); fw += bf2f(v.w);
        }
        *(float4*)&Cq[(g * NRP + row) * 4] = make_float4(fx, fy, fz, fw);
    }
    __syncthreads();

    const int q = tid & 3, dl = tid >> 2;
    const int d = d0 + dl;
    float4 av4 = *(const float4*)&A_param[d * DS + 4 * q];
    const float ea0 = __expf(-av4.x), ea1 = __expf(-av4.y);
    const float ea2 = __expf(-av4.z), ea3 = __expf(-av4.w);
    const float Dp = D_param[d];
    float h0 = 0.f, h1 = 0.f, h2 = 0.f, h3 = 0.f;

#define SCAN_STEP_WU(SD, AV, BI) {                                    \
        float sd = (SD), x = sd * (AV);                               \
        float4 Bv = *(const float4*)&Bq[(q * NRP + (BI)) * 4];        \
        h0 = fmaf(sd * ea0, h0, x * Bv.x);                           \
        h1 = fmaf(sd * ea1, h1, x * Bv.y);                           \
        h2 = fmaf(sd * ea2, h2, x * Bv.z);                           \
        h3 = fmaf(sd * ea3, h3, x * Bv.w); }

    // warm-up (no output)
    for (int i4 = 0; i4 < nw; i4 += 4) {
        ushort4 sdv = *(const ushort4*)&Ssh[dl * LDU + i4];
        ushort4 avv = *(const ushort4*)&Vsh[dl * LDU + i4];
        SCAN_STEP_WU(bf2f(sdv.x), bf2f(avv.x), i4 + 0);
        SCAN_STEP_WU(bf2f(sdv.y), bf2f(avv.y), i4 + 1);
        SCAN_STEP_WU(bf2f(sdv.z), bf2f(avv.z), i4 + 2);
        SCAN_STEP_WU(bf2f(sdv.w), bf2f(avv.w), i4 + 3);
    }

#define SCAN_STEP_OUT(SD, AV, BI, RV) {                               \
        float sd = (SD), av_ = (AV), x = sd * av_;                    \
        float4 Bv = *(const float4*)&Bq[(q * NRP + (BI)) * 4];        \
        float4 Cv = *(const float4*)&Cq[(q * NRP + (BI)) * 4];        \
        h0 = fmaf(sd * ea0, h0, x * Bv.x);                           \
        h1 = fmaf(sd * ea1, h1, x * Bv.y);                           \
        h2 = fmaf(sd * ea2, h2, x * Bv.z);                           \
        h3 = fmaf(sd * ea3, h3, x * Bv.w);                           \
        float r = h0 * Cv.x;                                          \
        r = fmaf(h1, Cv.y, r); r = fmaf(h2, Cv.z, r);                 \
        r = fmaf(h3, Cv.w, r);                                        \
        r = sum4(r);                                                  \
        RV = fmaf(Dp, av_, r); }

    // output region
    for (int i4 = nw; i4 < nrows; i4 += 4) {
        ushort4 sdv = *(const ushort4*)&Ssh[dl * LDU + i4];
        ushort4 avv = *(const ushort4*)&Vsh[dl * LDU + i4];
        float rv0, rv1, rv2, rv3;
        SCAN_STEP_OUT(bf2f(sdv.x), bf2f(avv.x), i4 + 0, rv0);
        SCAN_STEP_OUT(bf2f(sdv.y), bf2f(avv.y), i4 + 1, rv1);
        SCAN_STEP_OUT(bf2f(sdv.z), bf2f(avv.z), i4 + 2, rv2);
        SCAN_STEP_OUT(bf2f(sdv.w), bf2f(avv.w), i4 + 3, rv3);
        // lane q stores output step io+q (static select)
        float rvq = (q == 0) ? rv0 : (q == 1) ? rv1 : (q == 2) ? rv2 : rv3;
        int io = i4 - nw;
        Zsh[(io + q) * ZLD + dl] = f2bf(rvq);
    }
    __syncthreads();
    // write z with fused silu(g) gate (g read coalesced from global)
    for (int j = tid; j < TC * 16; j += 256) {
        int row = j >> 4, cq = (j & 15) * 4;
        ushort4 ov = *(const ushort4*)&Zsh[row * ZLD + cq];
        ushort4 gv = *(const ushort4*)&ab[(size_t)(tokout0 + row) * (2 * DM) + DM + d0 + cq];
        ushort4 o;
        float g0 = bf2f(gv.x), g1 = bf2f(gv.y), g2 = bf2f(gv.z), g3 = bf2f(gv.w);
        o.x = f2bf(bf2f(ov.x) * (g0 / (1.f + __expf(-g0))));
        o.y = f2bf(bf2f(ov.y) * (g1 / (1.f + __expf(-g1))));
        o.z = f2bf(bf2f(ov.z) * (g2 / (1.f + __expf(-g2))));
        o.w = f2bf(bf2f(ov.w) * (g3 / (1.f + __expf(-g3))));
        *(ushort4*)&z[(size_t)(tokout0 + row) * DM + d0 + cq] = o;
    }
#undef SCAN_STEP_WU
#undef SCAN_STEP_OUT
}

extern "C" void kernel_launch(void* const* d_in, const int* in_sizes, int n_in,
                              void* d_out, int out_size, void* d_ws, size_t ws_size,
                              hipStream_t stream) {
    const float* seq    = (const float*)d_in[0];
    const float* W_in   = (const float*)d_in[1];
    const float* W_out  = (const float*)d_in[2];
    const float* W_sB   = (const float*)d_in[3];
    const float* W_sC   = (const float*)d_in[4];
    const float* W_sD1  = (const float*)d_in[5];
    const float* W_sD2  = (const float*)d_in[6];
    const float* conv_w = (const float*)d_in[7];
    const float* conv_b = (const float*)d_in[8];
    const float* A_par  = (const float*)d_in[9];
    const float* D_par  = (const float*)d_in[10];
    float* out = (float*)d_out;

    char* ws = (char*)d_ws;
    const size_t MiB = 1024 * 1024;
    ushort_t* ab_bf    = (ushort_t*)(ws);                        // 16 MiB @0   (G1 -> conv, scan; dead after)
    ushort_t* part_out = (ushort_t*)(ws);                        // 16 MiB @0   (G8 bf16 partials, over dead ab)
    ushort_t* aconv_h  = (ushort_t*)(ws + 16 * MiB);             //  8 MiB @16  (dead after scan)
    ushort_t* sdel_h   = (ushort_t*)(ws + 24 * MiB);             //  8 MiB @24  (dead after scan)
    ushort_t* W_out_bf = (ushort_t*)(ws + 32 * MiB);             //  4 MiB @32
    ushort_t* W_sD2_bf = (ushort_t*)(ws + 37 * MiB);             // .5 MiB @37
    ushort_t* Wbcd     = (ushort_t*)(ws + 37 * MiB + 512*1024);  //  1 MiB
    ushort_t* seq_bf   = (ushort_t*)(ws + 39 * MiB);             //  4 MiB @39  (dead after G1)
    ushort_t* W_in_bf  = (ushort_t*)(ws + 43 * MiB);             //  8 MiB @43  (dead after G1)
    ushort_t* partK    = (ushort_t*)(ws + 43 * MiB);             //  8 MiB @43  (smallK partials, over W_in_bf; live thru G6+scan)
    ushort_t* z_bf     = (ushort_t*)(ws + 63 * MiB);             //  8 MiB @63  (scan -> G8)

    dim3 blk(256);

    // 1) all conversions + weight packing
    prep<<<dim3(8960), blk, 0, stream>>>(seq, W_in, W_out, W_sD2, W_sB, W_sC, W_sD1,
                                         seq_bf, W_in_bf, W_out_bf, W_sD2_bf, Wbcd);

    // 2) G1: ab = seq @ W_in^T (bf16 out)  M=2048 N=4096 K=1024, TM=64 -> 1024 blocks
    gemm_bt<64, 1><<<dim3(32, 32), blk, 0, stream>>>(seq_bf, W_in_bf, ab_bf, 1024, DI, DI, 2 * DM, nullptr, nullptr, 0);

    // 3) aconv = silu(causal_conv(a) + b) (bf16), one token/block, 8 d's/thread
    conv_silu<<<dim3(NTOK), blk, 0, stream>>>(ab_bf, conv_w, conv_b, aconv_h);

    // 4) split-K=8 small gemm: partK[z] = aconv @ Wbcd^T slice  N=256, K=256/slice (bf16 partials)
    gemm_bt<64, 5><<<dim3(2, 32, 8), blk, 0, stream>>>(aconv_h, Wbcd, nullptr, DM, DM, DM, 256, nullptr, partK, 2048 * 256);

    // 5) G6: sdel = softplus(D + d1 @ W_sD2^T) (bf16 out)  N=2048 K=128
    //    A = sum of 8 partials, cols 32..159 (ASUM8 reg-staged path)
    gemm_bt<64, 3, true><<<dim3(16, 32), blk, 0, stream>>>(partK + 32, W_sD2_bf, sdel_h, 128, 256, 128, DM, D_par, nullptr, 2048 * 256);

    // 6) windowed scan v3 -> z (B summed for all rows, C for output rows only)
    scan_win<<<dim3(DM / 64, LSEQ / TC, NB), blk, 0, stream>>>(
        sdel_h, aconv_h, partK, ab_bf, A_par, D_par, z_bf);

    // 7) G8 split-K=4: part_out[z] = z @ W_out^T slice  N=1024, K=512/slice, TM=64 -> 1024 blocks
    gemm_bt<64, 5><<<dim3(8, 32, 4), blk, 0, stream>>>(z_bf, W_out_bf, nullptr, DM, DM, DM, DI, nullptr, part_out, 2048 * 1024);

    // 8) out = sum_z part_out[z] (f32)
    reduce_out<<<dim3(2048), blk, 0, stream>>>(part_out, out);
}